// Round 10
// baseline (181.119 us; speedup 1.0000x reference)
//
#include <hip/hip_runtime.h>

// DCNv2 forward v8 — barrier-free swapped-operand MFMA.
// dcn_main: wave-private 16pos x 128o tiles; gathered x IS the B-operand fragment
// (lane = pos(l&15) x k-chunk(l>>4)); weights = A-operand streamed from L2.
// No LDS, no __syncthreads, meta 2-deep + gathers 1-deep register pipeline.
// K1 offconv_prep / K2 posprep / K4 combine unchanged from v7 (proven).

#define CIN 128

typedef __attribute__((ext_vector_type(4))) float f32x4;
typedef __attribute__((ext_vector_type(8))) short bf16x8;

struct f2 { float x, y; };   // 4-byte-aligned float pair (pair-load)

__device__ __forceinline__ unsigned short f2bf(float f) {
    unsigned u = __float_as_uint(f);
    u += 0x7FFF + ((u >> 16) & 1);          // RNE
    return (unsigned short)(u >> 16);
}
__device__ __forceinline__ float bf2f(unsigned short h) {
    return __uint_as_float(((unsigned)h) << 16);
}

// ---------------- K1: offset conv + weight prep ----------------
// blocks [0,512): conv, 64 rowgroups x 8 cgroups(16ch); block 256 = 4 rows x 64 w
// blocks [512,1088): wb prep  wb[S][o][k] (S = t*4 + c/32, k = c%32), hi/lo bf16
__global__ __launch_bounds__(256) void offconv_prep(const float* __restrict__ x,
                                                    const float* __restrict__ ofw,
                                                    const float* __restrict__ dcn_w,
                                                    float* __restrict__ part,
                                                    unsigned short* __restrict__ wbh,
                                                    unsigned short* __restrict__ wbl) {
    int bid = blockIdx.x;
    int tid = threadIdx.x;
    if (bid >= 512) {
        int i = (bid - 512) * 256 + tid;             // < 147456
        int S = i >> 12, o = (i >> 5) & 127, k = i & 31;
        int c = ((S & 3) << 5) + k, t = S >> 2;
        float w = dcn_w[((o << 7) + c) * 9 + t];
        unsigned short h = f2bf(w);
        wbh[i] = h;
        wbl[i] = f2bf(w - bf2f(h));
        return;
    }
    int rg = bid >> 3, cg = bid & 7;
    int lr = tid >> 6, ow = tid & 63;
    int row = (rg << 2) + lr;                        // n*64 + oh
    int n = row >> 6, oh = row & 63;
    int c0 = cg << 4;

    float acc[27];
#pragma unroll
    for (int oc = 0; oc < 27; ++oc) acc[oc] = 0.f;

    const float* xb0 = x + ((n * CIN + c0) << 12) + (oh << 6) + ow;
#pragma unroll 1
    for (int cl = 0; cl < 16; ++cl) {
        const float* xb = xb0 + (cl << 12);
        float xv[9];
#pragma unroll
        for (int kh = 0; kh < 3; ++kh) {
            int ih = oh + kh - 1;
            bool okr = ((unsigned)ih < 64u);
#pragma unroll
            for (int kw = 0; kw < 3; ++kw) {
                int iw = ow + kw - 1;
                xv[kh * 3 + kw] = (okr && (unsigned)iw < 64u) ? xb[(kh - 1) * 64 + (kw - 1)] : 0.f;
            }
        }
        const float* wp = ofw + (c0 + cl) * 9;       // wave-uniform -> scalar loads
#pragma unroll
        for (int t = 0; t < 9; ++t) {
            float xvt = xv[t];
#pragma unroll
            for (int oc = 0; oc < 27; ++oc)
                acc[oc] = fmaf(xvt, wp[oc * 1152 + t], acc[oc]);
        }
    }
    int sp = (oh << 6) + ow;
#pragma unroll
    for (int oc = 0; oc < 27; ++oc)
        part[((((cg << 2) + n) * 27 + oc) << 12) + sp] = acc[oc];
}

// ---------------- K2: per-(tap,pos) meta, pair-load form ----------------
// wq = slot weights (s0r1, s1r1, s0r2, s1r2); ob = (R1*64+Cb) | (R2*64+Cb)<<16
__global__ __launch_bounds__(256) void posprep(const float* __restrict__ part,
                                               const float* __restrict__ ob,
                                               float4* __restrict__ wq_t,
                                               unsigned* __restrict__ ob_t) {
    int gid = blockIdx.x * 256 + threadIdx.x;        // < 147456
    int k = gid >> 14, pos = gid & 16383;
    int n = pos >> 12, sp = pos & 4095;
    int oh = sp >> 6, ow = sp & 63;

    float oy = ob[2 * k], ox = ob[2 * k + 1], os = ob[18 + k];
#pragma unroll
    for (int cg = 0; cg < 8; ++cg) {
        const float* pb = part + ((((cg << 2) + n) * 27) << 12) + sp;
        oy += pb[(2 * k) << 12];
        ox += pb[(2 * k + 1) << 12];
        os += pb[(18 + k) << 12];
    }
    float m = 1.f / (1.f + expf(-os));
    float py = fminf(fmaxf((float)(oh + k / 3) + oy, 0.f), 65.f);
    float px = fminf(fmaxf((float)(ow + k % 3) + ox, 0.f), 65.f);
    float y1f = floorf(py), x1f = floorf(px);
    float lh = py - y1f, lw = px - x1f;
    float hh = 1.f - lh, hw = 1.f - lw;
    int y1 = (int)y1f, x1 = (int)x1f;
    int r1 = y1 - 1, r2 = y1, c1 = x1 - 1, c2 = x1;  // padded -> real coords; c2 = c1+1
    bool vr1 = (unsigned)r1 < 64u, vr2 = (unsigned)r2 < 64u;
    bool vc1 = (unsigned)c1 < 64u, vc2 = (unsigned)c2 < 64u;
    float w1 = (vr1 && vc1) ? hh * hw * m : 0.f;
    float w2 = (vr1 && vc2) ? hh * lw * m : 0.f;
    float w3 = (vr2 && vc1) ? lh * hw * m : 0.f;
    float w4 = (vr2 && vc2) ? lh * lw * m : 0.f;
    int Cb = min(max(c1, 0), 62);
    bool a0 = (c1 == Cb);                            // corner1 in slot0 (normal case)
    float s0r1 = a0 ? w1 : ((c2 == Cb) ? w2 : 0.f);
    float s1r1 = a0 ? w2 : ((c1 == Cb + 1) ? w1 : 0.f);
    float s0r2 = a0 ? w3 : ((c2 == Cb) ? w4 : 0.f);
    float s1r2 = a0 ? w4 : ((c1 == Cb + 1) ? w3 : 0.f);
    int R1 = min(max(r1, 0), 63), R2 = min(max(r2, 0), 63);
    unsigned o1 = (unsigned)(R1 * 64 + Cb), o2 = (unsigned)(R2 * 64 + Cb);
    wq_t[(k << 14) + pos] = make_float4(s0r1, s1r1, s0r2, s1r2);
    ob_t[(k << 14) + pos] = o1 | (o2 << 16);
}

// ---------------- K3: barrier-free swapped-operand MFMA gather-GEMM ----------------
// grid 1024 = 256 pos-tiles(64) x 4 kq; block 256 = 4 independent waves.
// wave = 16 pos x 128 o; 9 ksteps of 32 k. Gathered x = B-operand frag directly
// (lane: pos=l&15, channels (l>>4)*8..+8). Weights = A-operand streamed from wb.
// acc D[o][pos]: lane holds 4 o-rows x 1 pos per o-tile. No LDS, no barriers.
__global__ __launch_bounds__(256) void dcn_main(const float* __restrict__ x,
                                                const float4* __restrict__ wq_t,
                                                const unsigned* __restrict__ ob_t,
                                                const unsigned short* __restrict__ wbh,
                                                const unsigned short* __restrict__ wbl,
                                                float* __restrict__ pout) {
    int b0 = blockIdx.x;
    int bid = ((b0 & 7) << 7) | (b0 >> 3);           // XCD swizzle (1024 = 8*128)
    int tile = bid >> 2, q = bid & 3;
    int p0 = tile << 6;                              // 64 pos per block
    int tid = threadIdx.x;
    int lane = tid & 63, wave = tid >> 6;
    int fr = lane & 15, fg = lane >> 4;              // pos-in-16, k-chunk
    int pos = p0 + (wave << 4) + fr;                 // this lane's position
    int n = pos >> 12;                               // block-uniform (64 | 4096)
    const float* xn = x + ((long)n << 19);
    int S0 = q * 9;

    f32x4 acc[8];
#pragma unroll
    for (int j = 0; j < 8; ++j) acc[j] = (f32x4)0.f;

    float4 wv[3];                                    // meta, 3-slot rotation (static idx)
    unsigned obp[3];
    f2 g1[2][8], g2[2][8];                           // gathers, parity buffers
    bf16x8 xh, xl;

    // issue meta loads for kstep S_ into slot M (pure issue; no dependent use here)
#define META(M, S_) do {                                                            \
    int t_ = (S_) >> 2;                                                             \
    wv[M] = wq_t[(t_ << 14) + pos];                                                 \
    obp[M] = ob_t[(t_ << 14) + pos];                                                \
} while (0)

    // issue 16 pair-gathers for kstep S_ using meta slot M into parity P
#define GATHER(P, M, S_) do {                                                       \
    int o1_ = (int)(obp[M] & 0xffffu), o2_ = (int)(obp[M] >> 16);                   \
    const float* xb_ = xn + ((long)((((S_) & 3) << 5) + (fg << 3)) << 12);          \
    _Pragma("unroll")                                                               \
    for (int e_ = 0; e_ < 8; ++e_) {                                                \
        const float* xc_ = xb_ + (e_ << 12);                                        \
        g1[P][e_] = *(const f2*)(xc_ + o1_);                                        \
        g2[P][e_] = *(const f2*)(xc_ + o2_);                                        \
    }                                                                               \
} while (0)

    // pack parity P with meta slot M -> xh/xl (this lane's B-operand fragment)
#define PACK(P, M) do {                                                             \
    _Pragma("unroll")                                                               \
    for (int e_ = 0; e_ < 8; ++e_) {                                                \
        float v_ = wv[M].x * g1[P][e_].x + wv[M].y * g1[P][e_].y                    \
                 + wv[M].z * g2[P][e_].x + wv[M].w * g2[P][e_].y;                   \
        unsigned short h_ = f2bf(v_);                                               \
        xh[e_] = (short)h_;                                                         \
        xl[e_] = (short)f2bf(v_ - bf2f(h_));                                        \
    }                                                                               \
} while (0)

    // 8 o-tiles: stream W frags (A-operand: o-row = fr, k-chunk = fg), 3 mfma each
#define STEP(S_) do {                                                               \
    _Pragma("unroll")                                                               \
    for (int j_ = 0; j_ < 8; ++j_) {                                                \
        long a_ = ((long)(S_) << 12) + (((j_ << 4) + fr) << 5) + (fg << 3);         \
        bf16x8 wh_ = *(const bf16x8*)(wbh + a_);                                    \
        bf16x8 wl_ = *(const bf16x8*)(wbl + a_);                                    \
        acc[j_] = __builtin_amdgcn_mfma_f32_16x16x32_bf16(wh_, xh, acc[j_], 0, 0, 0); \
        acc[j_] = __builtin_amdgcn_mfma_f32_16x16x32_bf16(wl_, xh, acc[j_], 0, 0, 0); \
        acc[j_] = __builtin_amdgcn_mfma_f32_16x16x32_bf16(wh_, xl, acc[j_], 0, 0, 0); \
    }                                                                               \
} while (0)

    // prologue: meta for S0, S0+1; gathers for S0
    META(0, S0);
    META(1, S0 + 1);
    GATHER(0, 0, S0);

#pragma unroll
    for (int s = 0; s < 9; ++s) {
        if (s + 2 <= 8) META((s + 2) % 3, S0 + s + 2);        // 2 ahead (pure issue)
        if (s + 1 <= 8) GATHER((s + 1) & 1, (s + 1) % 3, S0 + s + 1); // 1 ahead
        PACK(s & 1, s % 3);                                   // waits only on own gathers
        STEP(S0 + s);
    }

    // epilogue: pout[q][o][pos] (o-major). lane: o-tile j -> o = j*16 + fg*4 + r, col = pos.
    float* op = pout + ((long)q << 21) + pos;
#pragma unroll
    for (int j = 0; j < 8; ++j) {
        long ob_ = (long)((j << 4) + (fg << 2)) << 14;
        op[ob_]               = acc[j][0];
        op[ob_ + (1L << 14)]  = acc[j][1];
        op[ob_ + (2L << 14)]  = acc[j][2];
        op[ob_ + (3L << 14)]  = acc[j][3];
    }
#undef META
#undef GATHER
#undef PACK
#undef STEP
}

// ---------------- K4: sum 4 K-partials, fully coalesced ----------------
// pout[q][o][pos], pos = n*4096+hw ; out[n][o][hw]. grid 2048 x 256 over float4s.
__global__ __launch_bounds__(256) void combine(const float4* __restrict__ pout4,
                                               float4* __restrict__ out4) {
    int i = blockIdx.x * 256 + threadIdx.x;          // < 524288
    int o = i >> 12, rem = i & 4095;
    int n = rem >> 10, hw4 = rem & 1023;
    float4 a = pout4[i];
    float4 b = pout4[i + (1 << 19)];
    float4 c = pout4[i + (2 << 19)];
    float4 d = pout4[i + (3 << 19)];
    float4 r = make_float4(a.x + b.x + c.x + d.x, a.y + b.y + c.y + d.y,
                           a.z + b.z + c.z + d.z, a.w + b.w + c.w + d.w);
    out4[(n << 17) + (o << 10) + hw4] = r;
}

extern "C" void kernel_launch(void* const* d_in, const int* in_sizes, int n_in,
                              void* d_out, int out_size, void* d_ws, size_t ws_size,
                              hipStream_t stream) {
    const float* x     = (const float*)d_in[0];      // [4,128,64,64]
    const float* ofw   = (const float*)d_in[1];      // [27,128,3,3]
    const float* ob    = (const float*)d_in[2];      // [27]
    const float* dcn_w = (const float*)d_in[3];      // [128,128,3,3]
    float* out = (float*)d_out;                      // [4,128,64,64]

    char* ws = (char*)d_ws;
    // pout (K3/K4) overlaps part (K1/K2) — disjoint lifetimes
    float*          pout = (float*)ws;                        // 33,554,432 B
    float*          part = (float*)ws;                        // 14,155,776 B (overlap)
    float4*         wq_t = (float4*)(ws + 33554432);          //  2,359,296 B
    unsigned*       ob_t = (unsigned*)(ws + 35913728);        //    589,824 B
    unsigned short* wbh  = (unsigned short*)(ws + 36503552);  //    294,912 B
    unsigned short* wbl  = (unsigned short*)(ws + 36798464);  //    294,912 B
    // total 37,093,376 B (< 44.7 MB proven budget)

    offconv_prep<<<dim3(1088), dim3(256), 0, stream>>>(x, ofw, dcn_w, part, wbh, wbl);
    posprep<<<dim3(576), dim3(256), 0, stream>>>(part, ob, wq_t, ob_t);
    dcn_main<<<dim3(1024), dim3(256), 0, stream>>>(x, wq_t, ob_t, wbh, wbl, pout);
    combine<<<dim3(2048), dim3(256), 0, stream>>>((const float4*)pout, (float4*)out);
}